// Round 9
// baseline (1420.251 us; speedup 1.0000x reference)
//
#include <hip/hip_runtime.h>
#include <math.h>

#define T 512
#define B 128
#define E 256
#define H 256
#define G 1024   // 4H
#define DA 25
#define HEADS 5
#define V 2080
#define NEGINF (-1e30f)

// ---------------- workspace layout (bytes) ----------------
static constexpr size_t WBT_OFF  = 0;           // [2][128 k2][256 j][4 gate] uint (f16 pair W_hh) 1,048,576
static constexpr size_t WIH_OFF  = 1048576;     // [2][1024 g][256 e] ushort (f16 W_ih)            1,048,576
static constexpr size_t WS1M_OFF = 2097152;     // [32 r][512 k] ushort (f16 W_s1, rows 25..31 = 0)   32,768
static constexpr size_t PX_OFF   = 2148352;     // [2][64][128][1024] f32     67,108,864
static constexpr size_t HC_OFF   = 69257216;    // [128][512][512] f32       134,217,728
static constexpr size_t HBUF_OFF = 203474944;   // [2][128 b][256 j] f32         262,144
static constexpr size_t CST_OFF  = 203737088;   // [2][128][256] f32 c-state     262,144
static constexpr size_t A_OFF    = 203999232;   // [128][5][512] f32           1,310,720
static constexpr size_t PART_OFF = 205309952;   // [128] f32                         512
static constexpr size_t EMBH_OFF = 205310464;   // [2080][256] ushort (f16 emb) 1,064,960
static constexpr size_t EMBH_END = EMBH_OFF + (size_t)V * E * 2;
// attnM partials overlay the (dead-by-then) PX region:
static constexpr size_t PM_OFF   = PX_OFF;                 // [8 tc][128 b][5 h][512] f32 = 10,485,760
static constexpr size_t PP_OFF   = PX_OFF + 10485760;      // [8 tc][128 b][16] f32     =     65,536

// ---- lstm6 dynamic LDS layout (bytes) ----
// part: [2 buf][4 kq][257] float4 = 32,896 ; wst: [28][256] uint4 = 114,688
static constexpr unsigned LSTM_LDS_BYTES = 147584;

typedef _Float16 half2v __attribute__((ext_vector_type(2)));
typedef _Float16 half8_ __attribute__((ext_vector_type(8)));
typedef float    f32x4  __attribute__((ext_vector_type(4)));

#if __has_builtin(__builtin_amdgcn_exp2f)
#define EXP2F_(x) __builtin_amdgcn_exp2f(x)
#else
#define EXP2F_(x) exp2f(x)
#endif
#if __has_builtin(__builtin_amdgcn_rcpf)
#define RCPF_(x) __builtin_amdgcn_rcpf(x)
#else
#define RCPF_(x) (1.0f / (x))
#endif

__device__ __forceinline__ float sigmoidf_(float x) { return 1.f / (1.f + expf(-x)); }

// fast sigmoid/tanh on v_exp/v_rcp; exact +-1 / 0..1 saturation at extremes
__device__ __forceinline__ float sigmoid_fast_(float x) {
    return RCPF_(1.f + EXP2F_(-1.44269504f * x));
}
__device__ __forceinline__ float tanh_fast_(float x) {
    return 1.f - 2.f * RCPF_(1.f + EXP2F_(2.88539008f * x));
}

__device__ __forceinline__ unsigned short f2h_(float f) {   // f32 -> f16 bits
    _Float16 h = (_Float16)f;
    unsigned short u;
    __builtin_memcpy(&u, &h, 2);
    return u;
}

// dot2: acc += w.lo*h.lo + w.hi*h.hi  (f32 accumulate)
__device__ __forceinline__ float fdot2_(unsigned w, half2v h, float acc) {
#if __has_builtin(__builtin_amdgcn_fdot2)
    half2v wv;
    __builtin_memcpy(&wv, &w, 4);
    return __builtin_amdgcn_fdot2(wv, h, acc, false);
#else
    unsigned short lo = (unsigned short)(w & 0xffffu), hi = (unsigned short)(w >> 16);
    _Float16 w0, w1;
    __builtin_memcpy(&w0, &lo, 2);
    __builtin_memcpy(&w1, &hi, 2);
    return fmaf((float)w0, (float)h[0], fmaf((float)w1, (float)h[1], acc));
#endif
}

__device__ __forceinline__ half2v packh2_(float a, float b) {
    half2v h;
    h[0] = (_Float16)a;
    h[1] = (_Float16)b;
    return h;
}

// ---------------- prep: pack W_hh + W_ih + W_s1 (+ emb) to f16 -------------
__global__ __launch_bounds__(256) void prep_kernel(const float* __restrict__ Whf,
                                                   const float* __restrict__ Whb,
                                                   const float* __restrict__ Wif,
                                                   const float* __restrict__ Wib,
                                                   const float* __restrict__ Ws1,
                                                   const float* __restrict__ emb,
                                                   unsigned short* __restrict__ wbt,
                                                   unsigned short* __restrict__ wih,
                                                   unsigned short* __restrict__ ws1m,
                                                   unsigned short* __restrict__ embh) {
    int idx = blockIdx.x * 256 + threadIdx.x;
    if (idx < 2 * G * H) {
        int d = idx >> 18;
        int rem = idx & 262143;
        int r = rem >> 8;                        // gate row 0..1023
        int k = rem & 255;                       // h index
        const float* W = d ? Whb : Whf;
        int gate = r >> 8, j = r & 255;
        int k2 = k >> 1, ke = k & 1;
        wbt[(((size_t)d * 128 + k2) * 256 + j) * 8 + gate * 2 + ke] = f2h_(W[(size_t)r * H + k]);
        const float* Wi = d ? Wib : Wif;
        wih[((size_t)d * G + r) * 256 + k] = f2h_(Wi[(size_t)r * E + k]);
    }
    if (idx < 32 * 512) {                        // W_s1 as [32][512] f16, rows 25..31 zero
        int r = idx >> 9, k = idx & 511;
        ws1m[idx] = (r < DA) ? f2h_(Ws1[r * 512 + k]) : (unsigned short)0;
    }
    if (embh && idx < V * E) embh[idx] = f2h_(emb[idx]);
}

// ---------------- input projection: MFMA f16 (64s x 64g x K=256 per block) ----
__global__ __launch_bounds__(256) void proj_kernel(const int* __restrict__ word_ids,
                                                   const int* __restrict__ lengths,
                                                   const float* __restrict__ emb,
                                                   const unsigned* __restrict__ embh,
                                                   const unsigned* __restrict__ wih,
                                                   const float* __restrict__ bf,
                                                   const float* __restrict__ bb,
                                                   float* __restrict__ pxc, int chunk) {
    int g0 = blockIdx.x * 64;
    int b  = blockIdx.y;
    int d  = blockIdx.z;
    int len = lengths[b];
    int t0 = chunk * 64;
    if (t0 >= len) return;
    const float* bias = d ? bb : bf;

    __shared__ _Float16 A_s[64][264];   // 33792 B, row stride 528 B (16B aligned)
    __shared__ _Float16 B_s[64][264];   // 33792 B

    int tid = threadIdx.x;
    int sr = tid >> 2, sq = tid & 3;    // staging: 4 threads per 512B row, 8 uint4 each

    {
        int t = t0 + sr;
        int src = d ? max(len - 1 - t, 0) : t;
        int wid = word_ids[b * T + src];
        if (embh) {
            const uint4* ap = (const uint4*)embh + (size_t)wid * 32;
            #pragma unroll
            for (int c = 0; c < 8; c++) {
                uint4 v = ap[sq * 8 + c];
                *(uint4*)&A_s[sr][(sq * 8 + c) * 8] = v;
            }
        } else {
            const float4* ep = (const float4*)(emb + (size_t)wid * E);
            #pragma unroll
            for (int c = 0; c < 8; c++) {
                float4 x0 = ep[(sq * 8 + c) * 2];
                float4 x1 = ep[(sq * 8 + c) * 2 + 1];
                half8_ hv;
                hv[0] = (_Float16)x0.x; hv[1] = (_Float16)x0.y;
                hv[2] = (_Float16)x0.z; hv[3] = (_Float16)x0.w;
                hv[4] = (_Float16)x1.x; hv[5] = (_Float16)x1.y;
                hv[6] = (_Float16)x1.z; hv[7] = (_Float16)x1.w;
                *(half8_*)&A_s[sr][(sq * 8 + c) * 8] = hv;
            }
        }
        const uint4* bp = (const uint4*)wih + ((size_t)d * G + g0 + sr) * 32;
        #pragma unroll
        for (int c = 0; c < 8; c++) {
            uint4 v = bp[sq * 8 + c];
            *(uint4*)&B_s[sr][(sq * 8 + c) * 8] = v;
        }
    }
    __syncthreads();

    int lane = tid & 63, wave = tid >> 6;
    int m0 = (wave >> 1) * 32;          // s quadrant base
    int n0 = (wave & 1) * 32;           // g quadrant base
    int lr = lane & 15, lq = lane >> 4;

    f32x4 acc00 = {0.f, 0.f, 0.f, 0.f}, acc01 = {0.f, 0.f, 0.f, 0.f};
    f32x4 acc10 = {0.f, 0.f, 0.f, 0.f}, acc11 = {0.f, 0.f, 0.f, 0.f};

    #pragma unroll
    for (int k0 = 0; k0 < E; k0 += 32) {
        int ka = k0 + lq * 8;
        half8_ af0 = *(const half8_*)&A_s[m0 + lr][ka];
        half8_ af1 = *(const half8_*)&A_s[m0 + 16 + lr][ka];
        half8_ bf0 = *(const half8_*)&B_s[n0 + lr][ka];
        half8_ bf1 = *(const half8_*)&B_s[n0 + 16 + lr][ka];
        acc00 = __builtin_amdgcn_mfma_f32_16x16x32_f16(af0, bf0, acc00, 0, 0, 0);
        acc01 = __builtin_amdgcn_mfma_f32_16x16x32_f16(af0, bf1, acc01, 0, 0, 0);
        acc10 = __builtin_amdgcn_mfma_f32_16x16x32_f16(af1, bf0, acc10, 0, 0, 0);
        acc11 = __builtin_amdgcn_mfma_f32_16x16x32_f16(af1, bf1, acc11, 0, 0, 0);
    }

    // C/D layout (m89-verified): col = lane&15, row = (lane>>4)*4 + reg
    float bia0 = bias[g0 + n0 + lr];
    float bia1 = bias[g0 + n0 + 16 + lr];
    #pragma unroll
    for (int mi = 0; mi < 2; mi++) {
        f32x4 ar0 = mi ? acc10 : acc00;
        f32x4 ar1 = mi ? acc11 : acc01;
        #pragma unroll
        for (int rr = 0; rr < 4; rr++) {
            int s = m0 + mi * 16 + lq * 4 + rr;
            float* dst = pxc + ((size_t)(d * 64 + s) * B + b) * G + g0;
            dst[n0 + lr]      = ar0[rr] + bia0;
            dst[n0 + 16 + lr] = ar1[rr] + bia1;
        }
    }
}

// ---------------- LSTM recurrence: symmetric finalize, ONE barrier/step ----
// grid (128 b, 2 dir); block 1024 = 16 waves; 1 block/CU.
// Dot phase: thread (kq=tid>>8, j=tid&255) computes 4-gate partials for j
// over its 32 k2 rows (7 LDS + 15 reg + 10 streamed); ALL groups write
// part[t&1][kq][j].  __syncthreads (the only barrier).  Finalize: wave w
// (group kq=w>>2) redundantly finalizes j' = 64*kq + lane — exactly the h
// values its OWN next dot phase needs.  c is loop-carried in lane regs;
// next hlv built in-register via 2 shuffles (no hh LDS, no 2nd barrier).
// part double-buffered by t-parity (WAR-safe across the single barrier).
// One wave per group does the global stores (no redundant write traffic).
__global__ __launch_bounds__(1024, 4) void lstm6_kernel(const int* __restrict__ lengths,
                                                        const unsigned* __restrict__ wbt,
                                                        const float* __restrict__ pxc,
                                                        float* __restrict__ hc_out,
                                                        float* __restrict__ hbuf,
                                                        float* __restrict__ cstate,
                                                        int chunk) {
    int b    = blockIdx.x;
    int d    = blockIdx.y;
    int tid  = threadIdx.x;
    int j    = tid & 255;
    int kq   = tid >> 8;               // 0..3 (group)
    int lane = tid & 63;
    int wave = tid >> 6;               // kq == wave>>2
    int jf   = kq * 64 + lane;         // finalize output index

    int len = lengths[b];
    int t0 = chunk * 64;
    if (t0 >= len) return;
    int tend = min(t0 + 64, len);

    extern __shared__ char smem[];
    float4* part = (float4*)smem;                 // [2][4][257]
    uint4*  wst  = (uint4*)(smem + 32896);        // [28][256]

    float* hbufg = hbuf + ((size_t)d * B + b) * 256;

    float c = 0.f, hreg = 0.f;
    unsigned hlv = 0u;
    if (chunk != 0) {
        c = cstate[((size_t)d * B + b) * H + jf];
        int m2 = kq * 64 + 2 * (lane & 31);
        half2v hv2 = packh2_(hbufg[m2], hbufg[m2 + 1]);
        __builtin_memcpy(&hlv, &hv2, 4);
        hreg = hbufg[jf];
    }

    // thread's W rows: k2 in [kq*32, kq*32+32), column j
    const uint4* wp  = (const uint4*)wbt + ((size_t)d * 128 + kq * 32) * 256 + j;
    const float* pxd = pxc + (size_t)d * 64 * B * G;

    // rows 0..6 -> LDS (thread-private: written+read by the same thread)
    #pragma unroll
    for (int r = 0; r < 7; r++)
        wst[(kq * 7 + r) * 256 + j] = wp[(size_t)r * 256];
    // rows 7..21 -> named registers (15 x uint4)
    uint4 wr0  = wp[7 * 256],  wr1  = wp[8 * 256],  wr2  = wp[9 * 256];
    uint4 wr3  = wp[10 * 256], wr4  = wp[11 * 256], wr5  = wp[12 * 256];
    uint4 wr6  = wp[13 * 256], wr7  = wp[14 * 256], wr8  = wp[15 * 256];
    uint4 wr9  = wp[16 * 256], wr10 = wp[17 * 256], wr11 = wp[18 * 256];
    uint4 wr12 = wp[19 * 256], wr13 = wp[20 * 256], wr14 = wp[21 * 256];

    for (int t = t0; t < tend; t++) {
        int s = t - t0;

        // px prefetch for the finalize of THIS step (consumed after barrier)
        const float* pxs = pxd + ((size_t)s * B + b) * G;
        float p0 = pxs[jf];
        float p1 = pxs[256 + jf];
        float p2 = pxs[512 + jf];
        float p3 = pxs[768 + jf];

        // streamed group 0 (rows 22..26) issued early
        uint4 v22 = wp[22 * 256], v23 = wp[23 * 256], v24 = wp[24 * 256];
        uint4 v25 = wp[25 * 256], v26 = wp[26 * 256];

        float a0 = 0.f, a1 = 0.f, a2 = 0.f, a3 = 0.f;

        #define HROW(IDX) __builtin_amdgcn_readlane(hlv, IDX)
        #define DOT4(WV, IDX)                                          \
            { unsigned hu = HROW(IDX); half2v hx;                      \
              __builtin_memcpy(&hx, &hu, 4);                           \
              a0 = fdot2_(WV.x, hx, a0); a1 = fdot2_(WV.y, hx, a1);    \
              a2 = fdot2_(WV.z, hx, a2); a3 = fdot2_(WV.w, hx, a3); }

        // LDS rows 0..6 (covers group-0 latency)
        #pragma unroll
        for (int r = 0; r < 7; r++) {
            uint4 wv = wst[(kq * 7 + r) * 256 + j];
            DOT4(wv, r)
        }
        // consume streamed group 0
        DOT4(v22, 22) DOT4(v23, 23) DOT4(v24, 24) DOT4(v25, 25) DOT4(v26, 26)
        // streamed group 1 (rows 27..31)
        uint4 v27 = wp[27 * 256], v28 = wp[28 * 256], v29 = wp[29 * 256];
        uint4 v30 = wp[30 * 256], v31 = wp[31 * 256];
        // register rows 7..21 (covers group-1 latency)
        DOT4(wr0, 7)   DOT4(wr1, 8)   DOT4(wr2, 9)   DOT4(wr3, 10)
        DOT4(wr4, 11)  DOT4(wr5, 12)  DOT4(wr6, 13)  DOT4(wr7, 14)
        DOT4(wr8, 15)  DOT4(wr9, 16)  DOT4(wr10, 17) DOT4(wr11, 18)
        DOT4(wr12, 19) DOT4(wr13, 20) DOT4(wr14, 21)
        // consume streamed group 1
        DOT4(v27, 27) DOT4(v28, 28) DOT4(v29, 29) DOT4(v30, 30) DOT4(v31, 31)
        #undef DOT4
        #undef HROW

        part[((size_t)(t & 1) * 4 + kq) * 257 + j] = make_float4(a0, a1, a2, a3);
        __syncthreads();           // the ONLY barrier per step

        // ---- symmetric finalize for jf (4x redundant within each group) ----
        const float4* pb = part + (size_t)(t & 1) * 4 * 257;
        float4 q0 = pb[0 * 257 + jf];
        float4 q1 = pb[1 * 257 + jf];
        float4 q2 = pb[2 * 257 + jf];
        float4 q3 = pb[3 * 257 + jf];
        float f0 = ((q0.x + q1.x) + (q2.x + q3.x)) + p0;
        float f1 = ((q0.y + q1.y) + (q2.y + q3.y)) + p1;
        float f2 = ((q0.z + q1.z) + (q2.z + q3.z)) + p2;
        float f3 = ((q0.w + q1.w) + (q2.w + q3.w)) + p3;

        float ig = sigmoid_fast_(f0), fg = sigmoid_fast_(f1), og = sigmoid_fast_(f3);
        c = fg * c + ig * tanh_fast_(f2);
        float h = og * tanh_fast_(c);
        hreg = h;

        if ((wave & 3) == 0) {
            int pos = d ? (len - 1 - t) : t;
            hc_out[((size_t)b * T + pos) * (2 * H) + d * H + jf] = h;
        }

        // build next hlv in-register: lane l needs pair (h[2m], h[2m+1]), m=l&31
        float hn = __shfl_down(h, 1);
        half2v pr = packh2_(h, hn);
        unsigned u;
        __builtin_memcpy(&u, &pr, 4);
        hlv = __shfl(u, 2 * (lane & 31), 64);
    }

    if ((wave & 3) == 0) {
        cstate[((size_t)d * B + b) * H + jf] = c;
        hbufg[jf] = hreg;
    }
}

// ---------------- attention logits via MFMA --------------------------------
__global__ __launch_bounds__(256) void logits_kernel(const int* __restrict__ lengths,
                                                     const float* __restrict__ hc,
                                                     const uint4* __restrict__ ws1m,
                                                     const float* __restrict__ Ws2,
                                                     float* __restrict__ S) {
    __shared__ _Float16 A_s[64][520];   // 66560 B (pad: pitch 1040 B ~ bank+4)
    __shared__ _Float16 B_s[32][520];   // 33280 B

    int b = blockIdx.y, tt = blockIdx.x;
    int tid = threadIdx.x;
    int len = lengths[b];
    int t0 = tt * 64;

    int lane = tid & 63, wave = tid >> 6;
    int lr = lane & 15, lq = lane >> 4;
    int m0 = wave * 16;

    if (t0 >= len) {
        if (lr < HEADS) {
            #pragma unroll
            for (int rr = 0; rr < 4; rr++) {
                int t = t0 + m0 + lq * 4 + rr;
                S[((size_t)b * HEADS + lr) * T + t] = NEGINF;
            }
        }
        return;
    }

    // stage B: 32 rows x 512 f16 = 2048 uint4; 8 per thread
    {
        #pragma unroll
        for (int i = 0; i < 8; i++) {
            int u = tid + i * 256;
            int r = u >> 6, c8 = u & 63;
            *(uint4*)&B_s[r][c8 * 8] = ws1m[u];
        }
    }
    // stage A: 64 hc rows -> f16; thread = (row = tid>>2, quarter = tid&3)
    {
        int row = tid >> 2, q = tid & 3;
        int t = t0 + row;
        const float4* ep = (const float4*)(hc + ((size_t)b * T + t) * 512 + q * 128);
        #pragma unroll
        for (int c = 0; c < 16; c++) {
            float4 x0 = ep[2 * c];
            float4 x1 = ep[2 * c + 1];
            half8_ hv;
            hv[0] = (_Float16)x0.x; hv[1] = (_Float16)x0.y;
            hv[2] = (_Float16)x0.z; hv[3] = (_Float16)x0.w;
            hv[4] = (_Float16)x1.x; hv[5] = (_Float16)x1.y;
            hv[6] = (_Float16)x1.z; hv[7] = (_Float16)x1.w;
            *(half8_*)&A_s[row][q * 128 + c * 8] = hv;
        }
    }
    __syncthreads();

    f32x4 acc0 = {0.f, 0.f, 0.f, 0.f};   // n-tile 0: r = lr
    f32x4 acc1 = {0.f, 0.f, 0.f, 0.f};   // n-tile 1: r = lr + 16
    #pragma unroll
    for (int ks = 0; ks < 16; ks++) {
        int ka = ks * 32 + lq * 8;
        half8_ af  = *(const half8_*)&A_s[m0 + lr][ka];
        half8_ bf0 = *(const half8_*)&B_s[lr][ka];
        half8_ bf1 = *(const half8_*)&B_s[16 + lr][ka];
        acc0 = __builtin_amdgcn_mfma_f32_16x16x32_f16(af, bf0, acc0, 0, 0, 0);
        acc1 = __builtin_amdgcn_mfma_f32_16x16x32_f16(af, bf1, acc1, 0, 0, 0);
    }

    // W_s2 weights for this lane's two r-slots (r=lr, r=lr+16)
    float w2a[HEADS], w2b[HEADS];
    #pragma unroll
    for (int h = 0; h < HEADS; h++) {
        w2a[h] = Ws2[h * DA + lr];
        w2b[h] = (lr + 16 < DA) ? Ws2[h * DA + 16 + lr] : 0.f;
    }

    #pragma unroll
    for (int rr = 0; rr < 4; rr++) {
        float y0 = tanhf(acc0[rr]);
        float y1 = tanhf(acc1[rr]);
        int t = t0 + m0 + lq * 4 + rr;
        float sv[HEADS];
        #pragma unroll
        for (int h = 0; h < HEADS; h++) {
            float v = y0 * w2a[h] + y1 * w2b[h];
            v += __shfl_xor(v, 1, 16);
            v += __shfl_xor(v, 2, 16);
            v += __shfl_xor(v, 4, 16);
            v += __shfl_xor(v, 8, 16);
            sv[h] = v;
        }
        if (lr < HEADS) {
            S[((size_t)b * HEADS + lr) * T + t] = (t < len) ? sv[lr] : NEGINF;
        }
    }
}

// ---------------- masked softmax over T, in place ----------------
__global__ __launch_bounds__(256) void softmax_kernel(float* __restrict__ S) {
    int row = blockIdx.x;
    float* p = S + (size_t)row * T;
    int tid = threadIdx.x;
    int lane = tid & 63, wave = tid >> 6;
    __shared__ float rr[4], ss[4];

    float mx = NEGINF;
    #pragma unroll
    for (int i = 0; i < 2; i++) mx = fmaxf(mx, p[tid + i * 256]);
    for (int off = 32; off; off >>= 1) mx = fmaxf(mx, __shfl_xor(mx, off, 64));
    if (lane == 0) rr[wave] = mx;
    __syncthreads();
    mx = fmaxf(fmaxf(rr[0], rr[1]), fmaxf(rr[2], rr[3]));

    float e[2], sum = 0.f;
    #pragma unroll
    for (int i = 0; i < 2; i++) { e[i] = expf(p[tid + i * 256] - mx); sum += e[i]; }
    for (int off = 32; off; off >>= 1) sum += __shfl_xor(sum, off, 64);
    if (lane == 0) ss[wave] = sum;
    __syncthreads();
    sum = ss[0] + ss[1] + ss[2] + ss[3];
    float inv = 1.f / sum;
    #pragma unroll
    for (int i = 0; i < 2; i++) p[tid + i * 256] = e[i] * inv;
}

// ---------------- attnM partials: 8 t-chunks x 128 b ----------------------
__global__ __launch_bounds__(256) void attnM_part_kernel(const int* __restrict__ lengths,
                                                         const float* __restrict__ A,
                                                         const float* __restrict__ hc,
                                                         float* __restrict__ pm,
                                                         float* __restrict__ pp) {
    int tc = blockIdx.x, b = blockIdx.y, tid = threadIdx.x;
    int len = lengths[b];
    int t0 = tc * 64;
    int tend = min(t0 + 64, len);
    const float* Ab  = A + (size_t)b * HEADS * T;
    const float* hcb = hc + (size_t)b * T * (2 * H);
    float acc[HEADS][2];
    #pragma unroll
    for (int h = 0; h < HEADS; h++) { acc[h][0] = 0.f; acc[h][1] = 0.f; }
    float p[10];
    #pragma unroll
    for (int i = 0; i < 10; i++) p[i] = 0.f;

    for (int t = t0; t < tend; t++) {
        float v0 = hcb[(size_t)t * (2 * H) + tid];
        float v1 = hcb[(size_t)t * (2 * H) + H + tid];
        float a0 = Ab[t], a1 = Ab[T + t], a2 = Ab[2 * T + t], a3 = Ab[3 * T + t], a4 = Ab[4 * T + t];
        acc[0][0] += a0 * v0; acc[0][1] += a0 * v1;
        acc[1][0] += a1 * v0; acc[1][1] += a1 * v1;
        acc[2][0] += a2 * v0; acc[2][1] += a2 * v1;
        acc[3][0] += a3 * v0; acc[3][1] += a3 * v1;
        acc[4][0] += a4 * v0; acc[4][1] += a4 * v1;
        if ((t & 255) == tid) {
            p[0] += a0 * a1; p[1] += a0 * a2; p[2] += a0 * a3; p[3] += a0 * a4;
            p[4] += a1 * a2; p[5] += a1 * a3; p[6] += a1 * a4;
            p[7] += a2 * a3; p[8] += a2 * a4; p[9] += a3 * a4;
        }
    }
    size_t base = ((size_t)tc * B + b) * (HEADS * 2 * H);
    #pragma unroll
    for (int h = 0; h < HEADS; h++) {
        pm[base + h * (2 * H) + tid]     = acc[h][0];
        pm[base + h * (2 * H) + H + tid] = acc[h][1];
    }

    __shared__ float red[10][4];
    int lane = tid & 63, wave = tid >> 6;
    #pragma unroll
    for (int i = 0; i < 10; i++) {
        float v = p[i];
        for (int off = 32; off; off >>= 1) v += __shfl_xor(v, off, 64);
        if (lane == 0) red[i][wave] = v;
    }
    __syncthreads();
    if (tid < 10)
        pp[((size_t)tc * B + b) * 16 + tid] =
            red[tid][0] + red[tid][1] + red[tid][2] + red[tid][3];
}

// ---------------- reduce partials -> out + penal per b ---------------------
__global__ __launch_bounds__(256) void attnM_reduce_kernel(const float* __restrict__ pm,
                                                           const float* __restrict__ pp,
                                                           float* __restrict__ out,
                                                           float* __restrict__ part) {
    int b = blockIdx.x, tid = threadIdx.x;
    #pragma unroll
    for (int h = 0; h < HEADS; h++) {
        float a0 = 0.f, a1 = 0.f;
        #pragma unroll
        for (int tc = 0; tc < 8; tc++) {
            size_t base = ((size_t)tc * B + b) * (HEADS * 2 * H) + h * (2 * H);
            a0 += pm[base + tid];
            a1 += pm[base + H + tid];
        }
        out[(size_t)b * (HEADS * 2 * H) + h * (2 * H) + tid]     = a0;
        out[(size_t)b * (HEADS * 2 * H) + h * (2 * H) + H + tid] = a1;
    }
    __shared__ float sred[10];
    if (tid < 10) {
        float P = 0.f;
        #pragma unroll
        for (int tc = 0; tc < 8; tc++) P += pp[((size_t)tc * B + b) * 16 + tid];
        sred[tid] = 2.f * P * P;
    }
    __syncthreads();
    if (tid == 0) {
        float s = 0.f;
        #pragma unroll
        for (int i = 0; i < 10; i++) s += sred[i];
        part[b] = s;
    }
}

__global__ __launch_bounds__(128) void final_kernel(const float* __restrict__ part,
                                                    float* __restrict__ out) {
    int tid = threadIdx.x;
    float v = part[tid];
    for (int off = 32; off; off >>= 1) v += __shfl_xor(v, off, 64);
    __shared__ float r2[2];
    if ((tid & 63) == 0) r2[tid >> 6] = v;
    __syncthreads();
    if (tid == 0) out[(size_t)B * HEADS * 2 * H] = (r2[0] + r2[1]) * (1.f / (float)B);
}

// ---------------- host launcher ----------------
extern "C" void kernel_launch(void* const* d_in, const int* in_sizes, int n_in,
                              void* d_out, int out_size, void* d_ws, size_t ws_size,
                              hipStream_t stream) {
    const int*   word_ids = (const int*)d_in[0];
    const int*   lengths  = (const int*)d_in[1];
    const float* emb      = (const float*)d_in[2];
    const float* W_ih_f   = (const float*)d_in[3];
    const float* W_hh_f   = (const float*)d_in[4];
    const float* b_f      = (const float*)d_in[5];
    const float* W_ih_b   = (const float*)d_in[6];
    const float* W_hh_b   = (const float*)d_in[7];
    const float* b_b      = (const float*)d_in[8];
    const float* W_s1     = (const float*)d_in[9];
    const float* W_s2     = (const float*)d_in[10];
    float* out = (float*)d_out;

    char* ws = (char*)d_ws;
    unsigned short* wbt16 = (unsigned short*)(ws + WBT_OFF);
    unsigned*       wbt   = (unsigned*)(ws + WBT_OFF);
    unsigned short* wih16 = (unsigned short*)(ws + WIH_OFF);
    unsigned*       wihu  = (unsigned*)(ws + WIH_OFF);
    unsigned short* ws1m16 = (unsigned short*)(ws + WS1M_OFF);
    const uint4*    ws1m4  = (const uint4*)(ws + WS1M_OFF);
    float* pxc    = (float*)(ws + PX_OFF);
    float* hc     = (float*)(ws + HC_OFF);
    float* hbuf   = (float*)(ws + HBUF_OFF);
    float* cstate = (float*)(ws + CST_OFF);
    float* Abuf   = (float*)(ws + A_OFF);
    float* part   = (float*)(ws + PART_OFF);
    float* pm     = (float*)(ws + PM_OFF);   // overlays dead pxc
    float* pp     = (float*)(ws + PP_OFF);
    bool have_embh = (ws_size >= EMBH_END);
    unsigned short* embh16 = have_embh ? (unsigned short*)(ws + EMBH_OFF) : nullptr;
    const unsigned* embhu  = have_embh ? (const unsigned*)(ws + EMBH_OFF) : nullptr;

    prep_kernel<<<2080, 256, 0, stream>>>(W_hh_f, W_hh_b, W_ih_f, W_ih_b, W_s1, emb,
                                          wbt16, wih16, ws1m16, embh16);

    for (int c = 0; c < 8; c++) {
        proj_kernel<<<dim3(16, 128, 2), 256, 0, stream>>>(
            word_ids, lengths, emb, embhu, wihu, b_f, b_b, pxc, c);
        lstm6_kernel<<<dim3(128, 2), 1024, LSTM_LDS_BYTES, stream>>>(
            lengths, wbt, pxc, hc, hbuf, cstate, c);
    }

    logits_kernel<<<dim3(8, 128), 256, 0, stream>>>(lengths, hc, ws1m4, W_s2, Abuf);
    softmax_kernel<<<B * HEADS, 256, 0, stream>>>(Abuf);
    attnM_part_kernel<<<dim3(8, 128), 256, 0, stream>>>(lengths, Abuf, hc, pm, pp);
    attnM_reduce_kernel<<<B, 256, 0, stream>>>(pm, pp, out, part);
    final_kernel<<<1, 128, 0, stream>>>(part, out);
}

// Round 10
// 1205.277 us; speedup vs baseline: 1.1784x; 1.1784x over previous
//
#include <hip/hip_runtime.h>
#include <math.h>

#define T 512
#define B 128
#define E 256
#define H 256
#define G 1024   // 4H
#define DA 25
#define HEADS 5
#define V 2080
#define NEGINF (-1e30f)

// ---------------- workspace layout (bytes) ----------------
static constexpr size_t WBT_OFF  = 0;           // [2][128 k2][256 j][4 gate] uint (f16 pair W_hh) 1,048,576
static constexpr size_t WIH_OFF  = 1048576;     // [2][1024 g][256 e] ushort (f16 W_ih)            1,048,576
static constexpr size_t WS1M_OFF = 2097152;     // [32 r][512 k] ushort (f16 W_s1, rows 25..31 = 0)   32,768
static constexpr size_t PX_OFF   = 2148352;     // [2][64][128][1024] f32     67,108,864
static constexpr size_t HC_OFF   = 69257216;    // [128][512][512] f32       134,217,728
static constexpr size_t HBUF_OFF = 203474944;   // [2][128 b][256 j] f32         262,144
static constexpr size_t CST_OFF  = 203737088;   // [2][128][256] f32 c-state     262,144
static constexpr size_t A_OFF    = 203999232;   // [128][5][512] f32           1,310,720
static constexpr size_t PART_OFF = 205309952;   // [128] f32                         512
static constexpr size_t EMBH_OFF = 205310464;   // [2080][256] ushort (f16 emb) 1,064,960
static constexpr size_t EMBH_END = EMBH_OFF + (size_t)V * E * 2;
// attnM partials overlay the (dead-by-then) PX region:
static constexpr size_t PM_OFF   = PX_OFF;                 // [8 tc][128 b][5 h][512] f32 = 10,485,760
static constexpr size_t PP_OFF   = PX_OFF + 10485760;      // [8 tc][128 b][16] f32     =     65,536

// ---- lstm6 dynamic LDS layout (bytes) ----
static constexpr unsigned LSTM_LDS_BYTES = 160304;

typedef _Float16 half2v __attribute__((ext_vector_type(2)));
typedef _Float16 half8_ __attribute__((ext_vector_type(8)));
typedef float    f32x4  __attribute__((ext_vector_type(4)));

#if __has_builtin(__builtin_amdgcn_exp2f)
#define EXP2F_(x) __builtin_amdgcn_exp2f(x)
#else
#define EXP2F_(x) exp2f(x)
#endif
#if __has_builtin(__builtin_amdgcn_rcpf)
#define RCPF_(x) __builtin_amdgcn_rcpf(x)
#else
#define RCPF_(x) (1.0f / (x))
#endif

__device__ __forceinline__ float sigmoidf_(float x) { return 1.f / (1.f + expf(-x)); }

// fast sigmoid/tanh on v_exp/v_rcp; exact +-1 / 0..1 saturation at extremes
__device__ __forceinline__ float sigmoid_fast_(float x) {
    return RCPF_(1.f + EXP2F_(-1.44269504f * x));
}
__device__ __forceinline__ float tanh_fast_(float x) {
    return 1.f - 2.f * RCPF_(1.f + EXP2F_(2.88539008f * x));
}

__device__ __forceinline__ unsigned short f2h_(float f) {   // f32 -> f16 bits
    _Float16 h = (_Float16)f;
    unsigned short u;
    __builtin_memcpy(&u, &h, 2);
    return u;
}

// dot2: acc += w.lo*h.lo + w.hi*h.hi  (f32 accumulate)
__device__ __forceinline__ float fdot2_(unsigned w, half2v h, float acc) {
#if __has_builtin(__builtin_amdgcn_fdot2)
    half2v wv;
    __builtin_memcpy(&wv, &w, 4);
    return __builtin_amdgcn_fdot2(wv, h, acc, false);
#else
    unsigned short lo = (unsigned short)(w & 0xffffu), hi = (unsigned short)(w >> 16);
    _Float16 w0, w1;
    __builtin_memcpy(&w0, &lo, 2);
    __builtin_memcpy(&w1, &hi, 2);
    return fmaf((float)w0, (float)h[0], fmaf((float)w1, (float)h[1], acc));
#endif
}

__device__ __forceinline__ half2v packh2_(float a, float b) {
    half2v h;
    h[0] = (_Float16)a;
    h[1] = (_Float16)b;
    return h;
}

// ---------------- prep: pack W_hh + W_ih + W_s1 (+ emb) to f16 -------------
__global__ __launch_bounds__(256) void prep_kernel(const float* __restrict__ Whf,
                                                   const float* __restrict__ Whb,
                                                   const float* __restrict__ Wif,
                                                   const float* __restrict__ Wib,
                                                   const float* __restrict__ Ws1,
                                                   const float* __restrict__ emb,
                                                   unsigned short* __restrict__ wbt,
                                                   unsigned short* __restrict__ wih,
                                                   unsigned short* __restrict__ ws1m,
                                                   unsigned short* __restrict__ embh) {
    int idx = blockIdx.x * 256 + threadIdx.x;
    if (idx < 2 * G * H) {
        int d = idx >> 18;
        int rem = idx & 262143;
        int r = rem >> 8;                        // gate row 0..1023
        int k = rem & 255;                       // h index
        const float* W = d ? Whb : Whf;
        int gate = r >> 8, j = r & 255;
        int k2 = k >> 1, ke = k & 1;
        wbt[(((size_t)d * 128 + k2) * 256 + j) * 8 + gate * 2 + ke] = f2h_(W[(size_t)r * H + k]);
        const float* Wi = d ? Wib : Wif;
        wih[((size_t)d * G + r) * 256 + k] = f2h_(Wi[(size_t)r * E + k]);
    }
    if (idx < 32 * 512) {                        // W_s1 as [32][512] f16, rows 25..31 zero
        int r = idx >> 9, k = idx & 511;
        ws1m[idx] = (r < DA) ? f2h_(Ws1[r * 512 + k]) : (unsigned short)0;
    }
    if (embh && idx < V * E) embh[idx] = f2h_(emb[idx]);
}

// ---------------- input projection: MFMA f16 (64s x 64g x K=256 per block) ----
__global__ __launch_bounds__(256) void proj_kernel(const int* __restrict__ word_ids,
                                                   const int* __restrict__ lengths,
                                                   const float* __restrict__ emb,
                                                   const unsigned* __restrict__ embh,
                                                   const unsigned* __restrict__ wih,
                                                   const float* __restrict__ bf,
                                                   const float* __restrict__ bb,
                                                   float* __restrict__ pxc, int chunk) {
    int g0 = blockIdx.x * 64;
    int b  = blockIdx.y;
    int d  = blockIdx.z;
    int len = lengths[b];
    int t0 = chunk * 64;
    if (t0 >= len) return;
    const float* bias = d ? bb : bf;

    __shared__ _Float16 A_s[64][264];   // 33792 B, row stride 528 B (16B aligned)
    __shared__ _Float16 B_s[64][264];   // 33792 B

    int tid = threadIdx.x;
    int sr = tid >> 2, sq = tid & 3;    // staging: 4 threads per 512B row, 8 uint4 each

    {
        int t = t0 + sr;
        int src = d ? max(len - 1 - t, 0) : t;
        int wid = word_ids[b * T + src];
        if (embh) {
            const uint4* ap = (const uint4*)embh + (size_t)wid * 32;
            #pragma unroll
            for (int c = 0; c < 8; c++) {
                uint4 v = ap[sq * 8 + c];
                *(uint4*)&A_s[sr][(sq * 8 + c) * 8] = v;
            }
        } else {
            const float4* ep = (const float4*)(emb + (size_t)wid * E);
            #pragma unroll
            for (int c = 0; c < 8; c++) {
                float4 x0 = ep[(sq * 8 + c) * 2];
                float4 x1 = ep[(sq * 8 + c) * 2 + 1];
                half8_ hv;
                hv[0] = (_Float16)x0.x; hv[1] = (_Float16)x0.y;
                hv[2] = (_Float16)x0.z; hv[3] = (_Float16)x0.w;
                hv[4] = (_Float16)x1.x; hv[5] = (_Float16)x1.y;
                hv[6] = (_Float16)x1.z; hv[7] = (_Float16)x1.w;
                *(half8_*)&A_s[sr][(sq * 8 + c) * 8] = hv;
            }
        }
        const uint4* bp = (const uint4*)wih + ((size_t)d * G + g0 + sr) * 32;
        #pragma unroll
        for (int c = 0; c < 8; c++) {
            uint4 v = bp[sq * 8 + c];
            *(uint4*)&B_s[sr][(sq * 8 + c) * 8] = v;
        }
    }
    __syncthreads();

    int lane = tid & 63, wave = tid >> 6;
    int m0 = (wave >> 1) * 32;          // s quadrant base
    int n0 = (wave & 1) * 32;           // g quadrant base
    int lr = lane & 15, lq = lane >> 4;

    f32x4 acc00 = {0.f, 0.f, 0.f, 0.f}, acc01 = {0.f, 0.f, 0.f, 0.f};
    f32x4 acc10 = {0.f, 0.f, 0.f, 0.f}, acc11 = {0.f, 0.f, 0.f, 0.f};

    #pragma unroll
    for (int k0 = 0; k0 < E; k0 += 32) {
        int ka = k0 + lq * 8;
        half8_ af0 = *(const half8_*)&A_s[m0 + lr][ka];
        half8_ af1 = *(const half8_*)&A_s[m0 + 16 + lr][ka];
        half8_ bf0 = *(const half8_*)&B_s[n0 + lr][ka];
        half8_ bf1 = *(const half8_*)&B_s[n0 + 16 + lr][ka];
        acc00 = __builtin_amdgcn_mfma_f32_16x16x32_f16(af0, bf0, acc00, 0, 0, 0);
        acc01 = __builtin_amdgcn_mfma_f32_16x16x32_f16(af0, bf1, acc01, 0, 0, 0);
        acc10 = __builtin_amdgcn_mfma_f32_16x16x32_f16(af1, bf0, acc10, 0, 0, 0);
        acc11 = __builtin_amdgcn_mfma_f32_16x16x32_f16(af1, bf1, acc11, 0, 0, 0);
    }

    // C/D layout (m89-verified): col = lane&15, row = (lane>>4)*4 + reg
    float bia0 = bias[g0 + n0 + lr];
    float bia1 = bias[g0 + n0 + 16 + lr];
    #pragma unroll
    for (int mi = 0; mi < 2; mi++) {
        f32x4 ar0 = mi ? acc10 : acc00;
        f32x4 ar1 = mi ? acc11 : acc01;
        #pragma unroll
        for (int rr = 0; rr < 4; rr++) {
            int s = m0 + mi * 16 + lq * 4 + rr;
            float* dst = pxc + ((size_t)(d * 64 + s) * B + b) * G + g0;
            dst[n0 + lr]      = ar0[rr] + bia0;
            dst[n0 + 16 + lr] = ar1[rr] + bia1;
        }
    }
}

// ---------------- LSTM recurrence: residency-split (r6-verified state) -----
// grid (128 b, 2 dir); block 1024 = 16 waves; LDS 160 KB -> 1 block/CU.
// 9 rows LDS + 23 rows declared-resident (compiler remats under 64-VGPR
// allocation; measured equivalent to explicit streaming — stream volume is
// NOT the limiter). Two barriers/step; narrow kq0 epilogue with fast
// exp2 activations, per-thread b16 hh write, deferred hc_out store.
// This exact structure measured 119.9 us/chunk (session best).
__global__ __launch_bounds__(1024, 4) void lstm6_kernel(const int* __restrict__ lengths,
                                                        const unsigned* __restrict__ wbt,
                                                        const float* __restrict__ pxc,
                                                        float* __restrict__ hc_out,
                                                        float* __restrict__ hbuf,
                                                        float* __restrict__ cstate,
                                                        int chunk) {
    int b   = blockIdx.x;
    int d   = blockIdx.y;
    int tid = threadIdx.x;
    int j  = tid & 255;
    int kq = tid >> 8;                 // 0..3 (wave-uniform)

    int len = lengths[b];
    int t0 = chunk * 64;
    if (t0 >= len) return;
    int tend = min(t0 + 64, len);

    extern __shared__ char smem[];
    unsigned* hh   = (unsigned*)smem;                // [128]
    float4*   part = (float4*)(smem + 512);          // [3][257]
    uint4*    wst  = (uint4*)(smem + 12848);         // [36][256]
    unsigned short* hh16 = (unsigned short*)smem;    // alias: h as f16[256]

    float* hbufg = hbuf + ((size_t)d * B + b) * 256;

    float c = 0.f, hreg = 0.f;
    if (chunk == 0) {
        if (tid < 128) hh[tid] = 0u;
    } else {
        if (kq == 0) c = cstate[((size_t)d * B + b) * H + j];
        if (tid < 128) {
            half2v hv2 = packh2_(hbufg[2 * tid], hbufg[2 * tid + 1]);
            unsigned hu;
            __builtin_memcpy(&hu, &hv2, 4);
            hh[tid] = hu;
        }
    }

    // thread's W rows: k2 in [kq*32, kq*32+32), column j
    const uint4* wp  = (const uint4*)wbt + ((size_t)d * 128 + kq * 32) * 256 + j;
    const float* pxd = pxc + (size_t)d * 64 * B * G;

    // stage k2 0..8 into LDS (thread-private; written+read by same thread)
    #pragma unroll
    for (int r = 0; r < 9; r++)
        wst[(kq * 9 + r) * 256 + j] = wp[(size_t)r * 256];
    // resident k2 9..31 in named registers (23 x uint4 = 92 VGPR raw)
    uint4 wr0  = wp[9 * 256],  wr1  = wp[10 * 256], wr2  = wp[11 * 256];
    uint4 wr3  = wp[12 * 256], wr4  = wp[13 * 256], wr5  = wp[14 * 256];
    uint4 wr6  = wp[15 * 256], wr7  = wp[16 * 256], wr8  = wp[17 * 256];
    uint4 wr9  = wp[18 * 256], wr10 = wp[19 * 256], wr11 = wp[20 * 256];
    uint4 wr12 = wp[21 * 256], wr13 = wp[22 * 256], wr14 = wp[23 * 256];
    uint4 wr15 = wp[24 * 256], wr16 = wp[25 * 256], wr17 = wp[26 * 256];
    uint4 wr18 = wp[27 * 256], wr19 = wp[28 * 256], wr20 = wp[29 * 256];
    uint4 wr21 = wp[30 * 256], wr22 = wp[31 * 256];
    __syncthreads();

    int hlane = kq * 32 + (tid & 31);   // lanes 32..63 duplicate 0..31 (broadcast pair, free)
    int pendpos = -1;

    for (int t = t0; t < tend; t++) {
        int s = t - t0;

        // deferred hc_out store for step t-1: drains during this dot phase
        if (kq == 0 && pendpos >= 0)
            hc_out[((size_t)b * T + pendpos) * (2 * H) + d * H + j] = hreg;

        float p0, p1, p2, p3;
        if (kq == 0) {
            const float* pxs = pxd + ((size_t)s * B + b) * G;
            p0 = pxs[j];
            p1 = pxs[256 + j];
            p2 = pxs[512 + j];
            p3 = pxs[768 + j];
        }

        unsigned hlv = hh[hlane];       // one LDS b32/lane; rows via readlane

        float a0 = 0.f, a1 = 0.f, a2 = 0.f, a3 = 0.f;

        #define HROW(IDX) __builtin_amdgcn_readlane(hlv, IDX)
        #define DOT4(WV, IDX)                                          \
            { unsigned hu = HROW(IDX); half2v hx;                      \
              __builtin_memcpy(&hx, &hu, 4);                           \
              a0 = fdot2_(WV.x, hx, a0); a1 = fdot2_(WV.y, hx, a1);    \
              a2 = fdot2_(WV.z, hx, a2); a3 = fdot2_(WV.w, hx, a3); }

        // LDS-cached k2 0..8 (ds_reads issue early; compiler interleaves waits)
        #pragma unroll
        for (int r = 0; r < 9; r++) {
            uint4 wv = wst[(kq * 9 + r) * 256 + j];
            DOT4(wv, r)
        }
        // register-resident k2 9..31
        DOT4(wr0, 9)   DOT4(wr1, 10)  DOT4(wr2, 11)  DOT4(wr3, 12)
        DOT4(wr4, 13)  DOT4(wr5, 14)  DOT4(wr6, 15)  DOT4(wr7, 16)
        DOT4(wr8, 17)  DOT4(wr9, 18)  DOT4(wr10, 19) DOT4(wr11, 20)
        DOT4(wr12, 21) DOT4(wr13, 22) DOT4(wr14, 23) DOT4(wr15, 24)
        DOT4(wr16, 25) DOT4(wr17, 26) DOT4(wr18, 27) DOT4(wr19, 28)
        DOT4(wr20, 29) DOT4(wr21, 30) DOT4(wr22, 31)
        #undef DOT4
        #undef HROW

        if (kq > 0) part[(kq - 1) * 257 + j] = make_float4(a0, a1, a2, a3);
        __syncthreads();           // barrier 1: partials ready; hh reads done

        if (kq == 0) {
            __builtin_amdgcn_s_setprio(1);
            #pragma unroll
            for (int q = 0; q < 3; q++) {
                float4 qv = part[q * 257 + j];
                a0 += qv.x; a1 += qv.y; a2 += qv.z; a3 += qv.w;
            }
            a0 += p0; a1 += p1; a2 += p2; a3 += p3;

            float ig = sigmoid_fast_(a0), fg = sigmoid_fast_(a1), og = sigmoid_fast_(a3);
            c = fg * c + ig * tanh_fast_(a2);
            float h = og * tanh_fast_(c);
            hreg = h;
            hh16[j] = f2h_(h);      // per-thread b16 write (no shfl)
            pendpos = d ? (len - 1 - t) : t;
            __builtin_amdgcn_s_setprio(0);
        }
        __syncthreads();           // barrier 2: hh updated before next reads
    }

    if (kq == 0) {
        if (pendpos >= 0)
            hc_out[((size_t)b * T + pendpos) * (2 * H) + d * H + j] = hreg;
        cstate[((size_t)d * B + b) * H + j] = c;
        hbufg[j] = hreg;
    }
}

// ---------------- attention logits via MFMA --------------------------------
__global__ __launch_bounds__(256) void logits_kernel(const int* __restrict__ lengths,
                                                     const float* __restrict__ hc,
                                                     const uint4* __restrict__ ws1m,
                                                     const float* __restrict__ Ws2,
                                                     float* __restrict__ S) {
    __shared__ _Float16 A_s[64][520];   // 66560 B (pad: pitch 1040 B ~ bank+4)
    __shared__ _Float16 B_s[32][520];   // 33280 B

    int b = blockIdx.y, tt = blockIdx.x;
    int tid = threadIdx.x;
    int len = lengths[b];
    int t0 = tt * 64;

    int lane = tid & 63, wave = tid >> 6;
    int lr = lane & 15, lq = lane >> 4;
    int m0 = wave * 16;

    if (t0 >= len) {
        if (lr < HEADS) {
            #pragma unroll
            for (int rr = 0; rr < 4; rr++) {
                int t = t0 + m0 + lq * 4 + rr;
                S[((size_t)b * HEADS + lr) * T + t] = NEGINF;
            }
        }
        return;
    }

    // stage B: 32 rows x 512 f16 = 2048 uint4; 8 per thread
    {
        #pragma unroll
        for (int i = 0; i < 8; i++) {
            int u = tid + i * 256;
            int r = u >> 6, c8 = u & 63;
            *(uint4*)&B_s[r][c8 * 8] = ws1m[u];
        }
    }
    // stage A: 64 hc rows -> f16; thread = (row = tid>>2, quarter = tid&3)
    {
        int row = tid >> 2, q = tid & 3;
        int t = t0 + row;
        const float4* ep = (const float4*)(hc + ((size_t)b * T + t) * 512 + q * 128);
        #pragma unroll
        for (int c = 0; c < 16; c++) {
            float4 x0 = ep[2 * c];
            float4 x1 = ep[2 * c + 1];
            half8_ hv;
            hv[0] = (_Float16)x0.x; hv[1] = (_Float16)x0.y;
            hv[2] = (_Float16)x0.z; hv[3] = (_Float16)x0.w;
            hv[4] = (_Float16)x1.x; hv[5] = (_Float16)x1.y;
            hv[6] = (_Float16)x1.z; hv[7] = (_Float16)x1.w;
            *(half8_*)&A_s[row][q * 128 + c * 8] = hv;
        }
    }
    __syncthreads();

    f32x4 acc0 = {0.f, 0.f, 0.f, 0.f};   // n-tile 0: r = lr
    f32x4 acc1 = {0.f, 0.f, 0.f, 0.f};   // n-tile 1: r = lr + 16
    #pragma unroll
    for (int ks = 0; ks < 16; ks++) {
        int ka = ks * 32 + lq * 8;
        half8_ af  = *(const half8_*)&A_s[m0 + lr][ka];
        half8_ bf0 = *(const half8_*)&B_s[lr][ka];
        half8_ bf1 = *(const half8_*)&B_s[16 + lr][ka];
        acc0 = __builtin_amdgcn_mfma_f32_16x16x32_f16(af, bf0, acc0, 0, 0, 0);
        acc1 = __builtin_amdgcn_mfma_f32_16x16x32_f16(af, bf1, acc1, 0, 0, 0);
    }

    // W_s2 weights for this lane's two r-slots (r=lr, r=lr+16)
    float w2a[HEADS], w2b[HEADS];
    #pragma unroll
    for (int h = 0; h < HEADS; h++) {
        w2a[h] = Ws2[h * DA + lr];
        w2b[h] = (lr + 16 < DA) ? Ws2[h * DA + 16 + lr] : 0.f;
    }

    #pragma unroll
    for (int rr = 0; rr < 4; rr++) {
        float y0 = tanhf(acc0[rr]);
        float y1 = tanhf(acc1[rr]);
        int t = t0 + m0 + lq * 4 + rr;
        float sv[HEADS];
        #pragma unroll
        for (int h = 0; h < HEADS; h++) {
            float v = y0 * w2a[h] + y1 * w2b[h];
            v += __shfl_xor(v, 1, 16);
            v += __shfl_xor(v, 2, 16);
            v += __shfl_xor(v, 4, 16);
            v += __shfl_xor(v, 8, 16);
            sv[h] = v;
        }
        if (lr < HEADS) {
            S[((size_t)b * HEADS + lr) * T + t] = (t < len) ? sv[lr] : NEGINF;
        }
    }
}

// ---------------- masked softmax over T, in place ----------------
__global__ __launch_bounds__(256) void softmax_kernel(float* __restrict__ S) {
    int row = blockIdx.x;
    float* p = S + (size_t)row * T;
    int tid = threadIdx.x;
    int lane = tid & 63, wave = tid >> 6;
    __shared__ float rr[4], ss[4];

    float mx = NEGINF;
    #pragma unroll
    for (int i = 0; i < 2; i++) mx = fmaxf(mx, p[tid + i * 256]);
    for (int off = 32; off; off >>= 1) mx = fmaxf(mx, __shfl_xor(mx, off, 64));
    if (lane == 0) rr[wave] = mx;
    __syncthreads();
    mx = fmaxf(fmaxf(rr[0], rr[1]), fmaxf(rr[2], rr[3]));

    float e[2], sum = 0.f;
    #pragma unroll
    for (int i = 0; i < 2; i++) { e[i] = expf(p[tid + i * 256] - mx); sum += e[i]; }
    for (int off = 32; off; off >>= 1) sum += __shfl_xor(sum, off, 64);
    if (lane == 0) ss[wave] = sum;
    __syncthreads();
    sum = ss[0] + ss[1] + ss[2] + ss[3];
    float inv = 1.f / sum;
    #pragma unroll
    for (int i = 0; i < 2; i++) p[tid + i * 256] = e[i] * inv;
}

// ---------------- attnM partials: 8 t-chunks x 128 b ----------------------
__global__ __launch_bounds__(256) void attnM_part_kernel(const int* __restrict__ lengths,
                                                         const float* __restrict__ A,
                                                         const float* __restrict__ hc,
                                                         float* __restrict__ pm,
                                                         float* __restrict__ pp) {
    int tc = blockIdx.x, b = blockIdx.y, tid = threadIdx.x;
    int len = lengths[b];
    int t0 = tc * 64;
    int tend = min(t0 + 64, len);
    const float* Ab  = A + (size_t)b * HEADS * T;
    const float* hcb = hc + (size_t)b * T * (2 * H);
    float acc[HEADS][2];
    #pragma unroll
    for (int h = 0; h < HEADS; h++) { acc[h][0] = 0.f; acc[h][1] = 0.f; }
    float p[10];
    #pragma unroll
    for (int i = 0; i < 10; i++) p[i] = 0.f;

    for (int t = t0; t < tend; t++) {
        float v0 = hcb[(size_t)t * (2 * H) + tid];
        float v1 = hcb[(size_t)t * (2 * H) + H + tid];
        float a0 = Ab[t], a1 = Ab[T + t], a2 = Ab[2 * T + t], a3 = Ab[3 * T + t], a4 = Ab[4 * T + t];
        acc[0][0] += a0 * v0; acc[0][1] += a0 * v1;
        acc[1][0] += a1 * v0; acc[1][1] += a1 * v1;
        acc[2][0] += a2 * v0; acc[2][1] += a2 * v1;
        acc[3][0] += a3 * v0; acc[3][1] += a3 * v1;
        acc[4][0] += a4 * v0; acc[4][1] += a4 * v1;
        if ((t & 255) == tid) {
            p[0] += a0 * a1; p[1] += a0 * a2; p[2] += a0 * a3; p[3] += a0 * a4;
            p[4] += a1 * a2; p[5] += a1 * a3; p[6] += a1 * a4;
            p[7] += a2 * a3; p[8] += a2 * a4; p[9] += a3 * a4;
        }
    }
    size_t base = ((size_t)tc * B + b) * (HEADS * 2 * H);
    #pragma unroll
    for (int h = 0; h < HEADS; h++) {
        pm[base + h * (2 * H) + tid]     = acc[h][0];
        pm[base + h * (2 * H) + H + tid] = acc[h][1];
    }

    __shared__ float red[10][4];
    int lane = tid & 63, wave = tid >> 6;
    #pragma unroll
    for (int i = 0; i < 10; i++) {
        float v = p[i];
        for (int off = 32; off; off >>= 1) v += __shfl_xor(v, off, 64);
        if (lane == 0) red[i][wave] = v;
    }
    __syncthreads();
    if (tid < 10)
        pp[((size_t)tc * B + b) * 16 + tid] =
            red[tid][0] + red[tid][1] + red[tid][2] + red[tid][3];
}

// ---------------- reduce partials -> out + penal per b ---------------------
__global__ __launch_bounds__(256) void attnM_reduce_kernel(const float* __restrict__ pm,
                                                           const float* __restrict__ pp,
                                                           float* __restrict__ out,
                                                           float* __restrict__ part) {
    int b = blockIdx.x, tid = threadIdx.x;
    #pragma unroll
    for (int h = 0; h < HEADS; h++) {
        float a0 = 0.f, a1 = 0.f;
        #pragma unroll
        for (int tc = 0; tc < 8; tc++) {
            size_t base = ((size_t)tc * B + b) * (HEADS * 2 * H) + h * (2 * H);
            a0 += pm[base + tid];
            a1 += pm[base + H + tid];
        }
        out[(size_t)b * (HEADS * 2 * H) + h * (2 * H) + tid]     = a0;
        out[(size_t)b * (HEADS * 2 * H) + h * (2 * H) + H + tid] = a1;
    }
    __shared__ float sred[10];
    if (tid < 10) {
        float P = 0.f;
        #pragma unroll
        for (int tc = 0; tc < 8; tc++) P += pp[((size_t)tc * B + b) * 16 + tid];
        sred[tid] = 2.f * P * P;
    }
    __syncthreads();
    if (tid == 0) {
        float s = 0.f;
        #pragma unroll
        for (int i = 0; i < 10; i++) s += sred[i];
        part[b] = s;
    }
}

__global__ __launch_bounds__(128) void final_kernel(const float* __restrict__ part,
                                                    float* __restrict__ out) {
    int tid = threadIdx.x;
    float v = part[tid];
    for (int off = 32; off; off >>= 1) v += __shfl_xor(v, off, 64);
    __shared__ float r2[2];
    if ((tid & 63) == 0) r2[tid >> 6] = v;
    __syncthreads();
    if (tid == 0) out[(size_t)B * HEADS * 2 * H] = (r2[0] + r2[1]) * (1.f / (float)B);
}

// ---------------- host launcher ----------------
extern "C" void kernel_launch(void* const* d_in, const int* in_sizes, int n_in,
                              void* d_out, int out_size, void* d_ws, size_t ws_size,
                              hipStream_t stream) {
    const int*   word_ids = (const int*)d_in[0];
    const int*   lengths  = (const int*)d_in[1];
    const float* emb      = (const float*)d_in[2];
    const float* W_ih_f   = (const float*)d_in[3];
    const float* W_hh_f   = (const float*)d_in[4];
    const float* b_f      = (const float*)d_in[5];
    const float* W_ih_b   = (const float*)d_in[6];
    const float* W_hh_b   = (const float*)d_in[7];
    const float* b_b      = (const float*)d_in[8];
    const float* W_s1     = (const float*)d_in[9];
    const float* W_s2     = (const float*)d_in[10];
    float* out = (float*)d_out;

    char* ws = (char*)d_ws;
    unsigned short* wbt16 = (unsigned short*)(ws + WBT_OFF);
    unsigned*       wbt   = (unsigned*)(ws + WBT_OFF);
    unsigned short* wih16 = (unsigned short*)(ws + WIH_OFF);
    unsigned*       wihu  = (unsigned*)(ws + WIH_OFF);
    unsigned short* ws1m16 = (unsigned short*)(ws + WS1M_OFF);
    const uint4*    ws1m4  = (const uint4*)(ws + WS1M_OFF);
    float* pxc    = (float*)(ws + PX_OFF);
    float* hc     = (float*)(ws + HC_OFF);
    float* hbuf   = (float*)(ws + HBUF_OFF);
    float* cstate = (float*)(ws + CST_OFF);
    float* Abuf   = (float*)(ws + A_OFF);
    float* part   = (float*)(ws + PART_OFF);
    float* pm     = (float*)(ws + PM_OFF);   // overlays dead pxc
    float* pp     = (float*)(ws + PP_OFF);
    bool have_embh = (ws_size >= EMBH_END);
    unsigned short* embh16 = have_embh ? (unsigned short*)(ws + EMBH_OFF) : nullptr;
    const unsigned* embhu  = have_embh ? (const unsigned*)(ws + EMBH_OFF) : nullptr;

    prep_kernel<<<2080, 256, 0, stream>>>(W_hh_f, W_hh_b, W_ih_f, W_ih_b, W_s1, emb,
                                          wbt16, wih16, ws1m16, embh16);

    for (int c = 0; c < 8; c++) {
        proj_kernel<<<dim3(16, 128, 2), 256, 0, stream>>>(
            word_ids, lengths, emb, embhu, wihu, b_f, b_b, pxc, c);
        lstm6_kernel<<<dim3(128, 2), 1024, LSTM_LDS_BYTES, stream>>>(
            lengths, wbt, pxc, hc, hbuf, cstate, c);
    }

    logits_kernel<<<dim3(8, 128), 256, 0, stream>>>(lengths, hc, ws1m4, W_s2, Abuf);
    softmax_kernel<<<B * HEADS, 256, 0, stream>>>(Abuf);
    attnM_part_kernel<<<dim3(8, 128), 256, 0, stream>>>(lengths, Abuf, hc, pm, pp);
    attnM_reduce_kernel<<<B, 256, 0, stream>>>(pm, pp, out, part);
    final_kernel<<<1, 128, 0, stream>>>(part, out);
}